// Round 14
// baseline (202.194 us; speedup 1.0000x reference)
//
#include <hip/hip_runtime.h>

// Pipeline_8400956031319: dual greedy NMS (8192 det + 8192 rpn, IOU>0.6,
// index order) + argmax masking.
//
// R13 rev — strip decomposition. R6-R13's "middle kernel" pinned at 30-45us
// across 6 structural variants; common factor = every block redundantly
// scanning all 8192 rows (512 blocks x 8192 = 4.2M classifications). Now:
//   K1 strip_kernel (32 blocks = 16 cell-row strips x 2 sets, 512 thr):
//     - scan input ONCE per block (batch-8 MLP loads, R12-proven),
//       classify rows into 128px 16x16 grid (box <=120 < 128 => only 3x3
//       neighborhoods overlap); strip cy stages rows with ccy in [cy-1,cy+1]
//     - bucket staged boxes by ccx in LDS (16-bucket hist + wave scan +
//       scatter from registers; members (ccy==cy) get a separate list)
//     - per member cell cx: flattened pair loop vs contiguous ccx run
//       [cx-1,cx+1] (pow2-padded index split: shift/mask, no int div)
//     - exact ref IOU; emit (ia<<13|ib) once (ia<ib: the strip owning the
//       smaller-index box as member is unique) to private per-strip region.
//   K2 solve_epi (32 blocks x 1024): gather set's edges (16 regions) to LDS,
//     Jacobi fixpoint keep[j] = !(exists i<j edge with keep[i]) (unique
//     fixpoint == greedy NMS; iterate until stable), write 512-row slice.

constexpr int NROWS = 8192;
constexpr int NKW   = 256;       // keep words (u32) per set
constexpr unsigned SCAP = 2048;  // staged boxes per strip (mean ~1536, sd ~35)
constexpr unsigned MCAP = 768;   // member boxes per strip (mean ~512)
constexpr unsigned RCAP = 4096;  // per-strip edge region (mean ~190)
constexpr unsigned ELDS = 16384; // solve LDS edge cache
#define IOU_T 0.6f

// ws layout: cnts[32] u32 @ 0 ; edges[32][RCAP] u32 @ 4096 (512 KB)
constexpr size_t OFF_EDGES = 4096;

// ---------------------------------------------------------------------------
// K1: strip scan + bucket + pair. grid = (16 strips, 2 sets) x 512 threads.
// ---------------------------------------------------------------------------
__global__ __launch_bounds__(512) void strip_kernel(
    const float* __restrict__ det, const float* __restrict__ rpn,
    unsigned* __restrict__ cnts, unsigned* __restrict__ edges)
{
  const int cy = blockIdx.x, set = blockIdx.y;
  const float* src  = (set == 0) ? det : rpn;
  const int    strd = (set == 0) ? 9 : 6;
  unsigned* myedges = edges + (size_t)(set * 16 + cy) * RCAP;

  __shared__ float Sx1[SCAP], Sy1[SCAP], Sx2[SCAP], Sy2[SCAP], Sar[SCAP];
  __shared__ unsigned Sid[SCAP];
  __shared__ unsigned mlist[MCAP];
  __shared__ unsigned shist[16], scur[16], soff[17];
  __shared__ unsigned mhist[16], mcur[16], moff[17];
  __shared__ unsigned eCnt, ovf;

  const int t = threadIdx.x;
  if (t < 16) { shist[t] = 0u; mhist[t] = 0u; scur[t] = 0u; mcur[t] = 0u; }
  if (t == 0) { eCnt = 0u; ovf = 0u; }
  __syncthreads();

  // ---- pass 1: load (batch-8 MLP), classify, histogram; keep class in regs
  int rcls[16];
  #pragma unroll
  for (int base = 0; base < 16; base += 8) {
    float rx1[8], ry1[8], rx2[8], ry2[8];
    #pragma unroll
    for (int k = 0; k < 8; ++k) {
      const int r = t + (base + k) * 512;
      const float* p = src + (size_t)r * strd + 1;
      rx1[k] = p[0]; ry1[k] = p[1]; rx2[k] = p[2]; ry2[k] = p[3];
    }
    #pragma unroll
    for (int k = 0; k < 8; ++k) {
      const float x1 = rx1[k], y1 = ry1[k], x2 = rx2[k], y2 = ry2[k];
      const float cxe = 0.5f * (x1 + x2), cye = 0.5f * (y1 + y2);
      const int ccx = min(15, max(0, (int)(cxe * (1.0f / 128.0f))));
      const int ccy = min(15, max(0, (int)(cye * (1.0f / 128.0f))));
      int cls = -1;
      if (ccy >= cy - 1 && ccy <= cy + 1) {
        cls = ccx | ((ccy == cy) ? 256 : 0);
        atomicAdd(&shist[ccx], 1u);
        if (ccy == cy) atomicAdd(&mhist[ccx], 1u);
      }
      rcls[base + k] = cls;
    }
  }
  __syncthreads();

  // ---- offsets: wave0 shuffle-scan over 16 buckets (both arrays at once)
  if (t < 64) {
    const unsigned sv = (t < 16) ? shist[t] : 0u;
    const unsigned mv = (t < 16) ? mhist[t] : 0u;
    unsigned si = sv, mi = mv;
    #pragma unroll
    for (int d = 1; d < 16; d <<= 1) {
      const unsigned a = __shfl_up(si, d);
      const unsigned b = __shfl_up(mi, d);
      if (t >= d) { si += a; mi += b; }
    }
    if (t < 16) { soff[t] = si - sv; moff[t] = mi - mv; }
    if (t == 15) { soff[16] = si; moff[16] = mi; }
  }
  __syncthreads();

  // ---- pass 2: reload (L2-hot, batch-8) + scatter into ccx-sorted LDS
  #pragma unroll
  for (int base = 0; base < 16; base += 8) {
    float rx1[8], ry1[8], rx2[8], ry2[8];
    #pragma unroll
    for (int k = 0; k < 8; ++k) {
      const int r = t + (base + k) * 512;
      const float* p = src + (size_t)r * strd + 1;
      rx1[k] = p[0]; ry1[k] = p[1]; rx2[k] = p[2]; ry2[k] = p[3];
    }
    #pragma unroll
    for (int k = 0; k < 8; ++k) {
      const int cls = rcls[base + k];
      if (cls >= 0) {
        const int ccx = cls & 15;
        const unsigned pos = soff[ccx] + atomicAdd(&scur[ccx], 1u);
        if (pos < SCAP) {
          const float x1 = rx1[k], y1 = ry1[k], x2 = rx2[k], y2 = ry2[k];
          Sx1[pos] = x1; Sy1[pos] = y1; Sx2[pos] = x2; Sy2[pos] = y2;
          Sar[pos] = fmaxf(x2 - x1, 0.0f) * fmaxf(y2 - y1, 0.0f); // ref area
          Sid[pos] = (unsigned)(t + (base + k) * 512);
          if (cls & 256) {
            const unsigned mp = moff[ccx] + atomicAdd(&mcur[ccx], 1u);
            if (mp < MCAP) mlist[mp] = pos; else atomicOr(&ovf, 1u);
          }
        } else atomicOr(&ovf, 1u);
      }
    }
  }
  __syncthreads();

  if (!ovf) {
    // ---- pair phase: per member cell, flattened vs its 3-column run.
    // pow2-padded split: p -> (member p>>sh, neighbor p&msk), no int div.
    for (int cx = 0; cx < 16; ++cx) {
      const unsigned nm = mhist[cx];
      if (!nm) continue;                               // uniform
      const unsigned mb = moff[cx];
      const int xlo = (cx > 0) ? cx - 1 : 0;
      const int xhi = (cx < 15) ? cx + 1 : 15;
      const unsigned lo = soff[xlo], hi = soff[xhi + 1];
      const unsigned nn = hi - lo;
      if (!nn) continue;
      const unsigned sh = (nn > 1) ? (32u - (unsigned)__builtin_clz(nn - 1)) : 0u;
      const unsigned msk = (1u << sh) - 1u;
      const unsigned tot = nm << sh;
      for (unsigned p = t; p < tot; p += 512) {
        const unsigned ni = p & msk;
        if (ni >= nn) continue;
        const unsigned m = mlist[mb + (p >> sh)];
        const unsigned n = lo + ni;
        const unsigned ia = Sid[m], ib = Sid[n];
        if (ia < ib) {                                 // emit-once; skips self
          const float ix1 = fmaxf(Sx1[m], Sx1[n]), iy1 = fmaxf(Sy1[m], Sy1[n]);
          const float ix2 = fminf(Sx2[m], Sx2[n]), iy2 = fminf(Sy2[m], Sy2[n]);
          const float inter = fmaxf(ix2 - ix1, 0.0f) * fmaxf(iy2 - iy1, 0.0f);
          if (inter > 0.0f) {
            const float uni = Sar[m] + Sar[n] - inter;        // ref order
            const float iou = inter / fmaxf(uni, 1e-9f);      // ref expr
            if (iou > IOU_T) {
              const unsigned slot = atomicAdd(&eCnt, 1u);     // LDS atomic
              if (slot < RCAP) myedges[slot] = (ia << 13) | ib;
            }
          }
        }
      }
    }
  } else {
    // exact fallback (never taken): member rows (ccy==cy) vs ALL rows.
    // iou>0.6 requires geometric overlap => identical edge set.
    for (int ra = 0; ra < NROWS; ++ra) {
      const float* pa = src + (size_t)ra * strd + 1;
      const float ax1 = pa[0], ay1 = pa[1], ax2 = pa[2], ay2 = pa[3];
      const float cye = 0.5f * (ay1 + ay2);
      const int ccy = min(15, max(0, (int)(cye * (1.0f / 128.0f))));
      if (ccy != cy) continue;                         // uniform skip
      const float aar = fmaxf(ax2 - ax1, 0.0f) * fmaxf(ay2 - ay1, 0.0f);
      for (int rb = t; rb < NROWS; rb += 512) {
        if ((unsigned)ra >= (unsigned)rb) continue;
        const float* pb = src + (size_t)rb * strd + 1;
        const float bx1 = pb[0], by1 = pb[1], bx2 = pb[2], by2 = pb[3];
        const float ix1 = fmaxf(ax1, bx1), iy1 = fmaxf(ay1, by1);
        const float ix2 = fminf(ax2, bx2), iy2 = fminf(ay2, by2);
        const float inter = fmaxf(ix2 - ix1, 0.0f) * fmaxf(iy2 - iy1, 0.0f);
        if (inter > 0.0f) {
          const float bar = fmaxf(bx2 - bx1, 0.0f) * fmaxf(by2 - by1, 0.0f);
          const float uni = aar + bar - inter;
          const float iou = inter / fmaxf(uni, 1e-9f);
          if (iou > IOU_T) {
            const unsigned slot = atomicAdd(&eCnt, 1u);
            if (slot < RCAP) myedges[slot] = ((unsigned)ra << 13) | (unsigned)rb;
          }
        }
      }
    }
  }
  __syncthreads();
  if (t == 0) cnts[set * 16 + cy] = min(eCnt, RCAP);
}

// ---------------------------------------------------------------------------
// K2: fixpoint + epilogue. grid = 32 blocks x 1024. set = blk>>4; each block
// solves its set's fixpoint (redundantly, ~3k edges, 16 regions) then writes
// rows [slice*512, slice*512+512) of its outputs.
// ---------------------------------------------------------------------------
__global__ __launch_bounds__(1024) void solve_epi_kernel(
    const float* __restrict__ det, const float* __restrict__ rpn,
    const unsigned* __restrict__ cnts, const unsigned* __restrict__ edges,
    float* __restrict__ out)
{
  const int blk = blockIdx.x;
  const int set = blk >> 4;
  const int slice = blk & 15;
  const unsigned* gedges = edges + (size_t)set * 16 * RCAP;

  __shared__ unsigned eL[ELDS];
  __shared__ unsigned rcnt[16], roff[17];
  __shared__ unsigned kbuf[2][NKW];
  __shared__ int changed[2];

  const int t = threadIdx.x;
  if (t < 16) rcnt[t] = min(cnts[set * 16 + t], RCAP);
  __syncthreads();

  // wave0 shuffle-scan of 16 region counts
  if (t < 64) {
    const unsigned v = (t < 16) ? rcnt[t] : 0u;
    unsigned incl = v;
    #pragma unroll
    for (int d = 1; d < 16; d <<= 1) {
      const unsigned a = __shfl_up(incl, d);
      if (t >= d) incl += a;
    }
    if (t < 16) roff[t] = incl - v;
    if (t == 15) roff[16] = incl;
  }
  if (t < NKW) kbuf[0][t] = 0xFFFFFFFFu;
  __syncthreads();

  const unsigned Etot = roff[16];
  const bool cached = (Etot <= ELDS);
  if (cached) {               // gather: 64 threads per region (~3 loads each)
    const unsigned rg = (unsigned)t >> 6, ln = (unsigned)t & 63u;
    const unsigned c = rcnt[rg], o = roff[rg];
    for (unsigned k = ln; k < c; k += 64u)
      eL[o + k] = gedges[(size_t)rg * RCAP + k];
  }
  __syncthreads();

  int cur = 0;
  for (int round = 0; round < NROWS + 8; ++round) {
    const int nxt = cur ^ 1;
    if (t == 0) changed[round & 1] = 0;
    if (t < NKW) kbuf[nxt][t] = 0xFFFFFFFFu;
    __syncthreads();

    if (cached) {
      for (unsigned e = t; e < Etot; e += 1024) {
        const unsigned pk = eL[e];
        const unsigned i = pk >> 13, j = pk & 8191u;
        if ((kbuf[cur][i >> 5] >> (i & 31)) & 1u)
          atomicAnd(&kbuf[nxt][j >> 5], ~(1u << (j & 31)));
      }
    } else {                  // exact slow path (never taken)
      const unsigned rg = (unsigned)t >> 6, ln = (unsigned)t & 63u;
      const unsigned c = rcnt[rg];
      for (unsigned k = ln; k < c; k += 64u) {
        const unsigned pk = gedges[(size_t)rg * RCAP + k];
        const unsigned i = pk >> 13, j = pk & 8191u;
        if ((kbuf[cur][i >> 5] >> (i & 31)) & 1u)
          atomicAnd(&kbuf[nxt][j >> 5], ~(1u << (j & 31)));
      }
    }
    __syncthreads();

    if (t < NKW && kbuf[nxt][t] != kbuf[cur][t]) changed[round & 1] = 1;
    __syncthreads();

    cur = nxt;
    if (!changed[round & 1]) break;  // F(x)==x -> the unique fixpoint
  }

  // epilogue slice: 512 rows per block
  const int r0 = slice * 512;
  if (set == 0) {
    for (int i = r0 + t; i < r0 + 512; i += 1024) {
      const bool kd = (kbuf[cur][i >> 5] >> (i & 31)) & 1u;
      const float* p = det + (size_t)i * 9;
      const float sc0 = p[5], sc1 = p[6], sc2 = p[7], sc3 = p[8];
      int am = 0; float best = sc0;
      if (sc1 > best) { best = sc1; am = 1; }   // first-max, like jnp.argmax
      if (sc2 > best) { best = sc2; am = 2; }
      if (sc3 > best) { best = sc3; am = 3; }
      const float vm = (kd && am != 0) ? 1.0f : 0.0f;
      const float im = (kd && am == 0) ? 1.0f : 0.0f;
      float* o0 = out + (size_t)i * 9;
      float* o1 = out + (size_t)NROWS * 9 + (size_t)i * 9;
      #pragma unroll
      for (int c = 0; c < 9; ++c) { const float v = p[c]; o0[c] = v * vm; o1[c] = v * im; }
    }
  } else {
    for (int i = r0 + t; i < r0 + 512; i += 1024) {
      const bool kr = (kbuf[cur][i >> 5] >> (i & 31)) & 1u;
      const float rm = kr ? 1.0f : 0.0f;
      const float* q = rpn + (size_t)i * 6;
      float* o2 = out + (size_t)NROWS * 18 + (size_t)i * 6;
      #pragma unroll
      for (int c = 0; c < 6; ++c) o2[c] = q[c] * rm;
    }
  }
}

// ---------------------------------------------------------------------------
extern "C" void kernel_launch(void* const* d_in, const int* in_sizes, int n_in,
                              void* d_out, int out_size, void* d_ws, size_t ws_size,
                              hipStream_t stream)
{
  const float* det = (const float*)d_in[0];   // 8192 x 9 fp32
  const float* rpn = (const float*)d_in[1];   // 8192 x 6 fp32
  float* out = (float*)d_out;                 // 8192*9 + 8192*9 + 8192*6 fp32

  char* ws = (char*)d_ws;
  unsigned* cnts  = (unsigned*)ws;            // [32] u32
  unsigned* edges = (unsigned*)(ws + OFF_EDGES);

  dim3 g1(16, 2);
  strip_kernel<<<g1, 512, 0, stream>>>(det, rpn, cnts, edges);
  solve_epi_kernel<<<32, 1024, 0, stream>>>(det, rpn, cnts, edges, out);
}

// Round 15
// 77.056 us; speedup vs baseline: 2.6240x; 2.6240x over previous
//
#include <hip/hip_runtime.h>

// Pipeline_8400956031319: dual greedy NMS (8192 det + 8192 rpn, IOU>0.6,
// index order) + argmax masking.
//
// R14 rev = R12 (best, 75.5us) with the scan's TWO 8-row load batches merged
// into ONE 16-row batch: 64 independent scalar loads in flight per thread ->
// a single memory-latency exposure per block (R12 had two). Everything else
// byte-identical to R12. (R13 strip decomposition regressed 2.7x: 32 blocks
// left the GPU empty at idle clock — reverted.)
//
//   K1 scanpair (512 blocks = (cell,set), 512 thr): batch-16 MLP scan,
//     classify rows into 128px 16x16 grid (box <=120 < 128 => only 3x3
//     neighborhoods can overlap), stage 3x3 neighborhood in LDS, flattened
//     pair loop, exact ref IOU, emit edges (i<<13|j, once via ia<ib) to
//     private per-block regions.
//   K2 solve_epi (32 blocks x 1024): gather set's edges to LDS, Jacobi
//     fixpoint keep[j] = !(exists i<j edge with keep[i]) (unique fixpoint ==
//     greedy NMS; iterate until stable), write 512-row output slice.

constexpr int NROWS = 8192;
constexpr int NKW   = 256;      // keep words (u32) per set
constexpr unsigned BCAP = 1536; // staged neighborhood cap (mean ~288)
constexpr unsigned ACAP = 512;  // cell-member cap (mean ~32)
constexpr unsigned RCAP = 2048; // per-block edge region cap (mean ~12)
constexpr unsigned ELDS = 16384;// solve LDS edge cache
#define IOU_T 0.6f

// ws layout: cnts[2][256] u32 @ 0 ; edges[2*256][RCAP] u32 @ 4096
constexpr size_t OFF_EDGES = 4096;

// ---------------------------------------------------------------------------
// K1: fused scan + pair. grid = (256 cells, 2 sets) x 512 threads.
// ---------------------------------------------------------------------------
__global__ __launch_bounds__(512) void scanpair_kernel(
    const float* __restrict__ det, const float* __restrict__ rpn,
    unsigned* __restrict__ cnts, unsigned* __restrict__ edges)
{
  const int cellid = blockIdx.x, set = blockIdx.y;
  const float* src  = (set == 0) ? det : rpn;
  const int    strd = (set == 0) ? 9 : 6;
  unsigned* myedges = edges + ((size_t)(set * 256 + cellid)) * RCAP;
  const int cx = cellid & 15, cy = cellid >> 4;

  __shared__ float Bx1[BCAP], By1[BCAP], Bx2[BCAP], By2[BCAP], Bar[BCAP];
  __shared__ unsigned Bid[BCAP];
  __shared__ unsigned aList[ACAP];
  __shared__ unsigned bCnt, aCnt, eCnt, ovf;

  const int t = threadIdx.x;
  if (t == 0) { bCnt = 0u; aCnt = 0u; eCnt = 0u; ovf = 0u; }
  __syncthreads();

  // scan: 16 rows/thread, ONE batch — all 64 loads issued before any use
  // (single latency exposure; R12 paid two).
  {
    float rx1[16], ry1[16], rx2[16], ry2[16];
    #pragma unroll
    for (int k = 0; k < 16; ++k) {
      const int r = t + k * 512;
      const float* p = src + (size_t)r * strd + 1;
      rx1[k] = p[0]; ry1[k] = p[1]; rx2[k] = p[2]; ry2[k] = p[3];
    }
    #pragma unroll
    for (int k = 0; k < 16; ++k) {
      const int r = t + k * 512;
      const float x1 = rx1[k], y1 = ry1[k], x2 = rx2[k], y2 = ry2[k];
      const float cxe = 0.5f * (x1 + x2), cye = 0.5f * (y1 + y2);
      const int ccx = min(15, max(0, (int)(cxe * (1.0f / 128.0f))));
      const int ccy = min(15, max(0, (int)(cye * (1.0f / 128.0f))));
      const int dx = ccx - cx, dy = ccy - cy;
      if (dx >= -1 && dx <= 1 && dy >= -1 && dy <= 1) {
        const unsigned s = atomicAdd(&bCnt, 1u);
        if (s < BCAP) {
          Bx1[s] = x1; By1[s] = y1; Bx2[s] = x2; By2[s] = y2;
          Bar[s] = fmaxf(x2 - x1, 0.0f) * fmaxf(y2 - y1, 0.0f); // ref area
          Bid[s] = (unsigned)r;
          if (dx == 0 && dy == 0) {
            const unsigned as = atomicAdd(&aCnt, 1u);
            if (as < ACAP) aList[as] = s; else atomicOr(&ovf, 1u);
          }
        } else atomicOr(&ovf, 1u);
      }
    }
  }
  __syncthreads();

  const unsigned nb = min(bCnt, BCAP);
  const unsigned na = min(aCnt, ACAP);

  if (!ovf) {
    // flattened pair phase: all tests independent, LDS-resident
    const unsigned tot = na * nb;
    for (unsigned p = t; p < tot; p += 512) {
      const unsigned ai = p / nb, x = p - ai * nb;
      const unsigned s = aList[ai];
      const unsigned ia = Bid[s], ib = Bid[x];
      if (ia < ib) {                                   // emit-once; skips self
        const float ix1 = fmaxf(Bx1[s], Bx1[x]), iy1 = fmaxf(By1[s], By1[x]);
        const float ix2 = fminf(Bx2[s], Bx2[x]), iy2 = fminf(By2[s], By2[x]);
        const float inter = fmaxf(ix2 - ix1, 0.0f) * fmaxf(iy2 - iy1, 0.0f);
        if (inter > 0.0f) {
          const float uni = Bar[s] + Bar[x] - inter;          // ref order
          const float iou = inter / fmaxf(uni, 1e-9f);        // ref expr
          if (iou > IOU_T) {
            const unsigned slot = atomicAdd(&eCnt, 1u);       // LDS atomic
            if (slot < RCAP) myedges[slot] = (ia << 13) | ib;
          }
        }
      }
    }
  } else {
    // exact fallback (never taken for this data): a = rows in this cell,
    // b = ALL rows; out-of-neighborhood pairs have inter==0 geometrically,
    // so semantics are identical to the fast path.
    for (int ra = 0; ra < NROWS; ++ra) {
      const float* pa = src + (size_t)ra * strd + 1;
      const float ax1 = pa[0], ay1 = pa[1], ax2 = pa[2], ay2 = pa[3];
      const float cxe = 0.5f * (ax1 + ax2), cye = 0.5f * (ay1 + ay2);
      const int ccx = min(15, max(0, (int)(cxe * (1.0f / 128.0f))));
      const int ccy = min(15, max(0, (int)(cye * (1.0f / 128.0f))));
      if (ccx != cx || ccy != cy) continue;            // uniform skip
      const float aar = fmaxf(ax2 - ax1, 0.0f) * fmaxf(ay2 - ay1, 0.0f);
      for (int rb = t; rb < NROWS; rb += 512) {
        if ((unsigned)ra >= (unsigned)rb) continue;
        const float* pb = src + (size_t)rb * strd + 1;
        const float bx1 = pb[0], by1 = pb[1], bx2 = pb[2], by2 = pb[3];
        const float ix1 = fmaxf(ax1, bx1), iy1 = fmaxf(ay1, by1);
        const float ix2 = fminf(ax2, bx2), iy2 = fminf(ay2, by2);
        const float inter = fmaxf(ix2 - ix1, 0.0f) * fmaxf(iy2 - iy1, 0.0f);
        if (inter > 0.0f) {
          const float bar = fmaxf(bx2 - bx1, 0.0f) * fmaxf(by2 - by1, 0.0f);
          const float uni = aar + bar - inter;
          const float iou = inter / fmaxf(uni, 1e-9f);
          if (iou > IOU_T) {
            const unsigned slot = atomicAdd(&eCnt, 1u);
            if (slot < RCAP) myedges[slot] = ((unsigned)ra << 13) | (unsigned)rb;
          }
        }
      }
    }
  }
  __syncthreads();
  if (t == 0) cnts[set * 256 + cellid] = min(eCnt, RCAP);
}

// ---------------------------------------------------------------------------
// K2: fixpoint + epilogue. grid = 32 blocks x 1024. set = blk>>4; each block
// solves its set's fixpoint (redundantly, ~3k edges) then writes rows
// [slice*512, slice*512+512) of its outputs.
// ---------------------------------------------------------------------------
__global__ __launch_bounds__(1024) void solve_epi_kernel(
    const float* __restrict__ det, const float* __restrict__ rpn,
    const unsigned* __restrict__ cnts, const unsigned* __restrict__ edges,
    float* __restrict__ out)
{
  const int blk = blockIdx.x;
  const int set = blk >> 4;
  const int slice = blk & 15;
  const unsigned* gedges = edges + (size_t)set * 256 * RCAP;

  __shared__ unsigned eL[ELDS];
  __shared__ unsigned rcnt[256], roff[256];
  __shared__ unsigned kbuf[2][NKW];
  __shared__ int changed[2];
  __shared__ unsigned Etot_sh;

  const int t = threadIdx.x;
  if (t < 256) rcnt[t] = min(cnts[set * 256 + t], RCAP);
  __syncthreads();

  // wave0 shuffle-scan of 256 region counts (4/lane)
  if (t < 64) {
    const unsigned h0 = rcnt[4 * t], h1 = rcnt[4 * t + 1];
    const unsigned h2 = rcnt[4 * t + 2], h3 = rcnt[4 * t + 3];
    const unsigned lsum = h0 + h1 + h2 + h3;
    unsigned incl = lsum;
    #pragma unroll
    for (int d = 1; d < 64; d <<= 1) {
      const unsigned v = __shfl_up(incl, d);
      if (t >= d) incl += v;
    }
    const unsigned base = incl - lsum;
    roff[4 * t] = base;               roff[4 * t + 1] = base + h0;
    roff[4 * t + 2] = base + h0 + h1; roff[4 * t + 3] = base + h0 + h1 + h2;
    if (t == 63) Etot_sh = incl;
  }
  if (t < NKW) kbuf[0][t] = 0xFFFFFFFFu;
  __syncthreads();

  const unsigned Etot = Etot_sh;
  const bool cached = (Etot <= ELDS);
  if (cached) {                 // gather: 4 threads per region (~3 loads ea)
    const unsigned rg = (unsigned)t >> 2, ln = (unsigned)t & 3u;
    const unsigned c = rcnt[rg], o = roff[rg];
    for (unsigned k = ln; k < c; k += 4u)
      eL[o + k] = gedges[(size_t)rg * RCAP + k];
  }
  __syncthreads();

  int cur = 0;
  for (int round = 0; round < NROWS + 8; ++round) {
    const int nxt = cur ^ 1;
    if (t == 0) changed[round & 1] = 0;
    if (t < NKW) kbuf[nxt][t] = 0xFFFFFFFFu;
    __syncthreads();

    if (cached) {
      for (unsigned e = t; e < Etot; e += 1024) {
        const unsigned pk = eL[e];
        const unsigned i = pk >> 13, j = pk & 8191u;
        if ((kbuf[cur][i >> 5] >> (i & 31)) & 1u)
          atomicAnd(&kbuf[nxt][j >> 5], ~(1u << (j & 31)));
      }
    } else {                    // exact slow path (never taken)
      for (unsigned r = (unsigned)t >> 2; r < 256u; r += 256u) {
        const unsigned c = rcnt[r];
        for (unsigned k = (unsigned)t & 3u; k < c; k += 4u) {
          const unsigned pk = gedges[(size_t)r * RCAP + k];
          const unsigned i = pk >> 13, j = pk & 8191u;
          if ((kbuf[cur][i >> 5] >> (i & 31)) & 1u)
            atomicAnd(&kbuf[nxt][j >> 5], ~(1u << (j & 31)));
        }
      }
    }
    __syncthreads();

    if (t < NKW && kbuf[nxt][t] != kbuf[cur][t]) changed[round & 1] = 1;
    __syncthreads();

    cur = nxt;
    if (!changed[round & 1]) break;  // F(x)==x -> the unique fixpoint
  }

  // epilogue slice: 512 rows per block
  const int r0 = slice * 512;
  if (set == 0) {
    for (int i = r0 + t; i < r0 + 512; i += 1024) {
      const bool kd = (kbuf[cur][i >> 5] >> (i & 31)) & 1u;
      const float* p = det + (size_t)i * 9;
      const float sc0 = p[5], sc1 = p[6], sc2 = p[7], sc3 = p[8];
      int am = 0; float best = sc0;
      if (sc1 > best) { best = sc1; am = 1; }   // first-max, like jnp.argmax
      if (sc2 > best) { best = sc2; am = 2; }
      if (sc3 > best) { best = sc3; am = 3; }
      const float vm = (kd && am != 0) ? 1.0f : 0.0f;
      const float im = (kd && am == 0) ? 1.0f : 0.0f;
      float* o0 = out + (size_t)i * 9;
      float* o1 = out + (size_t)NROWS * 9 + (size_t)i * 9;
      #pragma unroll
      for (int c = 0; c < 9; ++c) { const float v = p[c]; o0[c] = v * vm; o1[c] = v * im; }
    }
  } else {
    for (int i = r0 + t; i < r0 + 512; i += 1024) {
      const bool kr = (kbuf[cur][i >> 5] >> (i & 31)) & 1u;
      const float rm = kr ? 1.0f : 0.0f;
      const float* q = rpn + (size_t)i * 6;
      float* o2 = out + (size_t)NROWS * 18 + (size_t)i * 6;
      #pragma unroll
      for (int c = 0; c < 6; ++c) o2[c] = q[c] * rm;
    }
  }
}

// ---------------------------------------------------------------------------
extern "C" void kernel_launch(void* const* d_in, const int* in_sizes, int n_in,
                              void* d_out, int out_size, void* d_ws, size_t ws_size,
                              hipStream_t stream)
{
  const float* det = (const float*)d_in[0];   // 8192 x 9 fp32
  const float* rpn = (const float*)d_in[1];   // 8192 x 6 fp32
  float* out = (float*)d_out;                 // 8192*9 + 8192*9 + 8192*6 fp32

  char* ws = (char*)d_ws;
  unsigned* cnts  = (unsigned*)ws;            // [2][256] u32
  unsigned* edges = (unsigned*)(ws + OFF_EDGES);

  dim3 g1(256, 2);
  scanpair_kernel<<<g1, 512, 0, stream>>>(det, rpn, cnts, edges);
  solve_epi_kernel<<<32, 1024, 0, stream>>>(det, rpn, cnts, edges, out);
}